// Round 2
// baseline (273.301 us; speedup 1.0000x reference)
//
#include <hip/hip_runtime.h>
#include <stdint.h>

// ClusteringLayer: q = rownorm(1/(1 + ||x||^2 + ||c||^2 - 2 x@c^T))
// N=65536, D=512, K=512. bf16 MFMA GEMM fused with Student-t + row norm.
// R2: software-pipelined K-loop — double-buffered A/B (BK=32), one barrier
// per chunk, DMA/global loads issued a full compute-phase ahead of the
// vmcnt(0)-drain barrier that consumes them.

#define D 512
#define K 512
#define BM 64
#define BK 32
#define NCHUNK (D / BK)   // 16
#define THREADS 512

typedef __attribute__((ext_vector_type(8))) short short8;   // 8 x bf16
typedef __attribute__((ext_vector_type(4))) float floatx4;  // MFMA acc

// fp32 -> bf16 round-to-nearest-even
__device__ __forceinline__ uint16_t f2bf(float f) {
  uint32_t u = __float_as_uint(f);
  u += 0x7FFFu + ((u >> 16) & 1u);
  return (uint16_t)(u >> 16);
}

__device__ __forceinline__ uint2 pack4(float4 v) {
  uint2 p;
  p.x = (uint32_t)f2bf(v.x) | ((uint32_t)f2bf(v.y) << 16);
  p.y = (uint32_t)f2bf(v.z) | ((uint32_t)f2bf(v.w) << 16);
  return p;
}

// ---------------------------------------------------------------------------
// Prep: centroids fp32 -> bf16 pre-swizzled DMA image + ||c||^2.
// Image: chunk c (D/32), row r (0..511), group g (0..3, 8 bf16 = 16B):
//   elem_offset = (c*K + r)*32 + (g ^ ((r>>2)&3))*8
// Swizzle makes MFMA fragment reads (16 lanes, 16 consecutive rows, same g)
// land 2 lanes/bank-group = conflict-free (m136: 2-way is free).
// ---------------------------------------------------------------------------
__global__ __launch_bounds__(64)
void prep_kernel(const float* __restrict__ cent, float* __restrict__ csq,
                 uint16_t* __restrict__ bbf) {
  const int row  = blockIdx.x;     // 0..511
  const int lane = threadIdx.x;    // 0..63, 8 floats each
  const float4* src = (const float4*)(cent + (size_t)row * D + lane * 8);
  float4 v0 = src[0];
  float4 v1 = src[1];
  float ss = v0.x*v0.x + v0.y*v0.y + v0.z*v0.z + v0.w*v0.w
           + v1.x*v1.x + v1.y*v1.y + v1.z*v1.z + v1.w*v1.w;
  uint4 pk;
  { uint2 a = pack4(v0), b = pack4(v1); pk.x = a.x; pk.y = a.y; pk.z = b.x; pk.w = b.y; }
  const int c = lane >> 2;         // chunk 0..15 (32 cols each)
  const int g = lane & 3;          // 16B group within chunk
  const size_t eo = ((size_t)(c * K + row)) * 32 + (size_t)((g ^ ((row >> 2) & 3))) * 8;
  *(uint4*)(bbf + eo) = pk;
  #pragma unroll
  for (int m = 1; m < 64; m <<= 1) ss += __shfl_xor(ss, m);
  if (lane == 0) csq[row] = ss;
}

// ---------------------------------------------------------------------------
// Main fused kernel. Block = 64 rows x all 512 centroids, 8 waves,
// wave w owns cols [64w, 64w+64): 4x4 grid of 16x16x32 bf16 MFMA.
// ---------------------------------------------------------------------------
__global__ __launch_bounds__(THREADS, 4)
void cluster_main(const float* __restrict__ x, const uint16_t* __restrict__ bbf,
                  const float* __restrict__ csq, float* __restrict__ out) {
  __shared__ __align__(16) uint16_t lA[2][BM * BK];   // 2 x 4 KB
  __shared__ __align__(16) uint16_t lB[2][K * BK];    // 2 x 32 KB
  __shared__ float lcsq[K];                           // 2 KB
  __shared__ float lxsq[BM];
  __shared__ float lrow[BM];

  const int tid  = threadIdx.x;
  const int wave = tid >> 6;
  const int lane = tid & 63;
  const int p    = lane & 15;
  const int quad = lane >> 4;
  const int sw   = quad ^ (p >> 2);   // swizzled group for frag reads
  const int row0 = blockIdx.x * BM;

  lcsq[tid] = csq[tid];
  if (tid < BM) { lxsq[tid] = 0.f; lrow[tid] = 0.f; }

  // A staging: thread -> (row ar, 4-float sub-group sub); 1 float4 per chunk.
  const int ar  = tid >> 3;   // 0..63
  const int sub = tid & 7;    // 0..7 -> cols sub*4..sub*4+3
  const int aidx = (ar * 4 + ((sub >> 1) ^ ((ar >> 2) & 3))) * 8 + (sub & 1) * 4;
  const float* aptr = x + (size_t)(row0 + ar) * D + sub * 4;

  // B DMA: wave w copies rows [64w,64w+64) of the chunk image (4 KB) flat.
  const int bofs = wave * 2048 + lane * 8;   // uint16 units

  floatx4 acc[4][4];
  #pragma unroll
  for (int mi = 0; mi < 4; ++mi)
    #pragma unroll
    for (int ni = 0; ni < 4; ++ni)
      acc[mi][ni] = (floatx4){0.f, 0.f, 0.f, 0.f};

  float xacc;
  float4 areg;

  // --- prologue: stage chunk 0, prefetch chunk 1 ---
  {
    const uint16_t* src = bbf + bofs;
    uint16_t* dst = &lB[0][wave * 2048];
    #pragma unroll
    for (int j = 0; j < 4; ++j)
      __builtin_amdgcn_global_load_lds(
          (const __attribute__((address_space(1))) uint32_t*)(src + j * 512),
          (__attribute__((address_space(3))) uint32_t*)(dst + j * 512),
          16, 0, 0);
    float4 a0 = *(const float4*)(aptr);
    xacc = a0.x*a0.x + a0.y*a0.y + a0.z*a0.z + a0.w*a0.w;
    *(uint2*)&lA[0][aidx] = pack4(a0);
    areg = *(const float4*)(aptr + BK);   // chunk 1, in flight
  }
  __syncthreads();
  {   // DMA chunk 1 -> buf 1 (no readers yet; drained at end of iter 0)
    const uint16_t* src = bbf + (size_t)1 * (K * BK) + bofs;
    uint16_t* dst = &lB[1][wave * 2048];
    #pragma unroll
    for (int j = 0; j < 4; ++j)
      __builtin_amdgcn_global_load_lds(
          (const __attribute__((address_space(1))) uint32_t*)(src + j * 512),
          (__attribute__((address_space(3))) uint32_t*)(dst + j * 512),
          16, 0, 0);
  }

  for (int c = 0; c < NCHUNK; ++c) {
    const int buf = c & 1;

    // stage A[c+1] from regs into the other A buffer (its readers finished
    // before the barrier that ended iter c-1)
    if (c + 1 < NCHUNK) {
      xacc += areg.x*areg.x + areg.y*areg.y + areg.z*areg.z + areg.w*areg.w;
      *(uint2*)&lA[(c + 1) & 1][aidx] = pack4(areg);
    }
    // prefetch A[c+2] (global->reg, overlaps MFMA below)
    if (c + 2 < NCHUNK) areg = *(const float4*)(aptr + (c + 2) * BK);

    // compute chunk c
    short8 af[4], bfr[4];
    #pragma unroll
    for (int mi = 0; mi < 4; ++mi) {
      const int r = mi * 16 + p;
      af[mi] = *(const short8*)&lA[buf][r * 32 + sw * 8];
    }
    #pragma unroll
    for (int ni = 0; ni < 4; ++ni) {
      const int r = wave * 64 + ni * 16 + p;
      bfr[ni] = *(const short8*)&lB[buf][r * 32 + sw * 8];
    }
    #pragma unroll
    for (int mi = 0; mi < 4; ++mi)
      #pragma unroll
      for (int ni = 0; ni < 4; ++ni)
        acc[mi][ni] = __builtin_amdgcn_mfma_f32_16x16x32_bf16(
            af[mi], bfr[ni], acc[mi][ni], 0, 0, 0);

    __syncthreads();  // publishes buf[c+1] (DMA had full compute in flight)

    // DMA B[c+2] into the buffer compute-c just vacated
    if (c + 2 < NCHUNK) {
      const uint16_t* src = bbf + (size_t)(c + 2) * (K * BK) + bofs;
      uint16_t* dst = &lB[buf][wave * 2048];
      #pragma unroll
      for (int j = 0; j < 4; ++j)
        __builtin_amdgcn_global_load_lds(
            (const __attribute__((address_space(1))) uint32_t*)(src + j * 512),
            (__attribute__((address_space(3))) uint32_t*)(dst + j * 512),
            16, 0, 0);
    }
  }

  // ||x||^2 per row (8 partial contributors per row)
  atomicAdd(&lxsq[ar], xacc);
  __syncthreads();

  // --- epilogue: q = rcp(1 + xsq + csq - 2*dot); fused row-normalize ---
  float xs[4][4];
  #pragma unroll
  for (int mi = 0; mi < 4; ++mi)
    #pragma unroll
    for (int rr = 0; rr < 4; ++rr)
      xs[mi][rr] = lxsq[mi * 16 + quad * 4 + rr];
  float cs[4];
  #pragma unroll
  for (int ni = 0; ni < 4; ++ni)
    cs[ni] = lcsq[wave * 64 + ni * 16 + p];

  float rp[4][4];
  #pragma unroll
  for (int mi = 0; mi < 4; ++mi)
    #pragma unroll
    for (int rr = 0; rr < 4; ++rr)
      rp[mi][rr] = 0.f;

  #pragma unroll
  for (int mi = 0; mi < 4; ++mi)
    #pragma unroll
    for (int ni = 0; ni < 4; ++ni)
      #pragma unroll
      for (int rr = 0; rr < 4; ++rr) {
        const float d = 1.0f + xs[mi][rr] + cs[ni] - 2.0f * acc[mi][ni][rr];
        const float q = __builtin_amdgcn_rcpf(d);  // d ~ 1000, 1 ulp is plenty
        acc[mi][ni][rr] = q;
        rp[mi][rr] += q;
      }

  #pragma unroll
  for (int mi = 0; mi < 4; ++mi)
    #pragma unroll
    for (int rr = 0; rr < 4; ++rr) {
      float v = rp[mi][rr];
      v += __shfl_xor(v, 1);
      v += __shfl_xor(v, 2);
      v += __shfl_xor(v, 4);
      v += __shfl_xor(v, 8);
      if (p == 0) atomicAdd(&lrow[mi * 16 + quad * 4 + rr], v);
    }
  __syncthreads();

  #pragma unroll
  for (int mi = 0; mi < 4; ++mi) {
    #pragma unroll
    for (int rr = 0; rr < 4; ++rr) {
      const int row = mi * 16 + quad * 4 + rr;
      const float inv = __builtin_amdgcn_rcpf(lrow[row]);
      float* orow = out + (size_t)(row0 + row) * K + wave * 64 + p;
      #pragma unroll
      for (int ni = 0; ni < 4; ++ni)
        orow[ni * 16] = acc[mi][ni][rr] * inv;
    }
  }
}

extern "C" void kernel_launch(void* const* d_in, const int* in_sizes, int n_in,
                              void* d_out, int out_size, void* d_ws, size_t ws_size,
                              hipStream_t stream) {
  const float* x    = (const float*)d_in[0];
  const float* cent = (const float*)d_in[1];
  float* out = (float*)d_out;

  // ws: csq[512] floats (2KB) | bbf bf16 image (512KB)
  float*    csq = (float*)d_ws;
  uint16_t* bbf = (uint16_t*)((char*)d_ws + 2048);

  const int N = in_sizes[0] / D;      // 65536
  prep_kernel<<<K, 64, 0, stream>>>(cent, csq, bbf);
  cluster_main<<<N / BM, THREADS, 0, stream>>>(x, bbf, csq, out);
}

// Round 3
// 272.787 us; speedup vs baseline: 1.0019x; 1.0019x over previous
//
#include <hip/hip_runtime.h>
#include <stdint.h>

// ClusteringLayer: q = rownorm(1/(1 + ||x||^2 + ||c||^2 - 2 x@c^T))
// N=65536, D=512, K=512. bf16 MFMA GEMM fused with Student-t + row norm.
// R3: R2's pipelined K-loop (double-buffered A/B, BK=32, 1 barrier/chunk)
// with the bank-conflict swizzle FIXED for 64-byte rows: phys_group =
// logical_group ^ ((row>>1)&3), making every 8-lane ds_read_b128 phase hit
// 8 distinct 16B granules (R2's quad^(p>>2) hit only 4 -> 4.19M conflicts).

#define D 512
#define K 512
#define BM 64
#define BK 32
#define NCHUNK (D / BK)   // 16
#define THREADS 512

typedef __attribute__((ext_vector_type(8))) short short8;   // 8 x bf16
typedef __attribute__((ext_vector_type(4))) float floatx4;  // MFMA acc

// fp32 -> bf16 round-to-nearest-even
__device__ __forceinline__ uint16_t f2bf(float f) {
  uint32_t u = __float_as_uint(f);
  u += 0x7FFFu + ((u >> 16) & 1u);
  return (uint16_t)(u >> 16);
}

__device__ __forceinline__ uint2 pack4(float4 v) {
  uint2 p;
  p.x = (uint32_t)f2bf(v.x) | ((uint32_t)f2bf(v.y) << 16);
  p.y = (uint32_t)f2bf(v.z) | ((uint32_t)f2bf(v.w) << 16);
  return p;
}

// ---------------------------------------------------------------------------
// Prep: centroids fp32 -> bf16 pre-swizzled DMA image + ||c||^2.
// Image: chunk c (D/32), row r (0..511), 16B group g (0..3):
//   elem_offset = (c*K + r)*32 + (g ^ ((r>>1)&3))*8
// ---------------------------------------------------------------------------
__global__ __launch_bounds__(64)
void prep_kernel(const float* __restrict__ cent, float* __restrict__ csq,
                 uint16_t* __restrict__ bbf) {
  const int row  = blockIdx.x;     // 0..511
  const int lane = threadIdx.x;    // 0..63, 8 floats each
  const float4* src = (const float4*)(cent + (size_t)row * D + lane * 8);
  float4 v0 = src[0];
  float4 v1 = src[1];
  float ss = v0.x*v0.x + v0.y*v0.y + v0.z*v0.z + v0.w*v0.w
           + v1.x*v1.x + v1.y*v1.y + v1.z*v1.z + v1.w*v1.w;
  uint4 pk;
  { uint2 a = pack4(v0), b = pack4(v1); pk.x = a.x; pk.y = a.y; pk.z = b.x; pk.w = b.y; }
  const int c = lane >> 2;         // chunk 0..15 (32 cols each)
  const int g = lane & 3;          // 16B group within chunk
  const size_t eo = ((size_t)(c * K + row)) * 32 + (size_t)(g ^ ((row >> 1) & 3)) * 8;
  *(uint4*)(bbf + eo) = pk;
  #pragma unroll
  for (int m = 1; m < 64; m <<= 1) ss += __shfl_xor(ss, m);
  if (lane == 0) csq[row] = ss;
}

// ---------------------------------------------------------------------------
// Main fused kernel. Block = 64 rows x all 512 centroids, 8 waves,
// wave w owns cols [64w, 64w+64): 4x4 grid of 16x16x32 bf16 MFMA.
// ---------------------------------------------------------------------------
__global__ __launch_bounds__(THREADS, 4)
void cluster_main(const float* __restrict__ x, const uint16_t* __restrict__ bbf,
                  const float* __restrict__ csq, float* __restrict__ out) {
  __shared__ __align__(16) uint16_t lA[2][BM * BK];   // 2 x 4 KB
  __shared__ __align__(16) uint16_t lB[2][K * BK];    // 2 x 32 KB
  __shared__ float lcsq[K];                           // 2 KB
  __shared__ float lxsq[BM];
  __shared__ float lrow[BM];

  const int tid  = threadIdx.x;
  const int wave = tid >> 6;
  const int lane = tid & 63;
  const int p    = lane & 15;
  const int quad = lane >> 4;
  // frag-read physical group: quad ^ ((r>>1)&3); row bases are ≡0 mod 16 so
  // ((r>>1)&3) == ((p>>1)&3) -> lane-constant.
  const int sw   = quad ^ ((p >> 1) & 3);
  const int row0 = blockIdx.x * BM;

  lcsq[tid] = csq[tid];
  if (tid < BM) { lxsq[tid] = 0.f; lrow[tid] = 0.f; }

  // A staging: thread -> (row ar, 4-float sub-group sub); 1 float4 per chunk.
  const int ar  = tid >> 3;   // 0..63
  const int sub = tid & 7;    // 0..7 -> cols sub*4..sub*4+3
  const int aidx = (ar * 4 + ((sub >> 1) ^ ((ar >> 1) & 3))) * 8 + (sub & 1) * 4;
  const float* aptr = x + (size_t)(row0 + ar) * D + sub * 4;

  // B DMA: wave w copies rows [64w,64w+64) of the chunk image (4 KB) flat.
  const int bofs = wave * 2048 + lane * 8;   // uint16 units

  floatx4 acc[4][4];
  #pragma unroll
  for (int mi = 0; mi < 4; ++mi)
    #pragma unroll
    for (int ni = 0; ni < 4; ++ni)
      acc[mi][ni] = (floatx4){0.f, 0.f, 0.f, 0.f};

  float xacc;
  float4 areg;

  // --- prologue: stage chunk 0, prefetch chunk 1 ---
  {
    const uint16_t* src = bbf + bofs;
    uint16_t* dst = &lB[0][wave * 2048];
    #pragma unroll
    for (int j = 0; j < 4; ++j)
      __builtin_amdgcn_global_load_lds(
          (const __attribute__((address_space(1))) uint32_t*)(src + j * 512),
          (__attribute__((address_space(3))) uint32_t*)(dst + j * 512),
          16, 0, 0);
    float4 a0 = *(const float4*)(aptr);
    xacc = a0.x*a0.x + a0.y*a0.y + a0.z*a0.z + a0.w*a0.w;
    *(uint2*)&lA[0][aidx] = pack4(a0);
    areg = *(const float4*)(aptr + BK);   // chunk 1, in flight
  }
  __syncthreads();
  {   // DMA chunk 1 -> buf 1 (no readers yet; drained at end of iter 0)
    const uint16_t* src = bbf + (size_t)1 * (K * BK) + bofs;
    uint16_t* dst = &lB[1][wave * 2048];
    #pragma unroll
    for (int j = 0; j < 4; ++j)
      __builtin_amdgcn_global_load_lds(
          (const __attribute__((address_space(1))) uint32_t*)(src + j * 512),
          (__attribute__((address_space(3))) uint32_t*)(dst + j * 512),
          16, 0, 0);
  }

  for (int c = 0; c < NCHUNK; ++c) {
    const int buf = c & 1;

    // stage A[c+1] from regs into the other A buffer (its readers finished
    // before the barrier that ended iter c-1)
    if (c + 1 < NCHUNK) {
      xacc += areg.x*areg.x + areg.y*areg.y + areg.z*areg.z + areg.w*areg.w;
      *(uint2*)&lA[(c + 1) & 1][aidx] = pack4(areg);
    }
    // prefetch A[c+2] (global->reg, overlaps MFMA below)
    if (c + 2 < NCHUNK) areg = *(const float4*)(aptr + (c + 2) * BK);

    // compute chunk c
    short8 af[4], bfr[4];
    #pragma unroll
    for (int mi = 0; mi < 4; ++mi) {
      const int r = mi * 16 + p;
      af[mi] = *(const short8*)&lA[buf][r * 32 + sw * 8];
    }
    #pragma unroll
    for (int ni = 0; ni < 4; ++ni) {
      const int r = wave * 64 + ni * 16 + p;
      bfr[ni] = *(const short8*)&lB[buf][r * 32 + sw * 8];
    }
    #pragma unroll
    for (int mi = 0; mi < 4; ++mi)
      #pragma unroll
      for (int ni = 0; ni < 4; ++ni)
        acc[mi][ni] = __builtin_amdgcn_mfma_f32_16x16x32_bf16(
            af[mi], bfr[ni], acc[mi][ni], 0, 0, 0);

    __syncthreads();  // publishes buf[c+1] (DMA had full compute in flight)

    // DMA B[c+2] into the buffer compute-c just vacated
    if (c + 2 < NCHUNK) {
      const uint16_t* src = bbf + (size_t)(c + 2) * (K * BK) + bofs;
      uint16_t* dst = &lB[buf][wave * 2048];
      #pragma unroll
      for (int j = 0; j < 4; ++j)
        __builtin_amdgcn_global_load_lds(
            (const __attribute__((address_space(1))) uint32_t*)(src + j * 512),
            (__attribute__((address_space(3))) uint32_t*)(dst + j * 512),
            16, 0, 0);
    }
  }

  // ||x||^2 per row (8 partial contributors per row)
  atomicAdd(&lxsq[ar], xacc);
  __syncthreads();

  // --- epilogue: q = rcp(1 + xsq + csq - 2*dot); fused row-normalize ---
  float xs[4][4];
  #pragma unroll
  for (int mi = 0; mi < 4; ++mi)
    #pragma unroll
    for (int rr = 0; rr < 4; ++rr)
      xs[mi][rr] = lxsq[mi * 16 + quad * 4 + rr];
  float cs[4];
  #pragma unroll
  for (int ni = 0; ni < 4; ++ni)
    cs[ni] = lcsq[wave * 64 + ni * 16 + p];

  float rp[4][4];
  #pragma unroll
  for (int mi = 0; mi < 4; ++mi)
    #pragma unroll
    for (int rr = 0; rr < 4; ++rr)
      rp[mi][rr] = 0.f;

  #pragma unroll
  for (int mi = 0; mi < 4; ++mi)
    #pragma unroll
    for (int ni = 0; ni < 4; ++ni)
      #pragma unroll
      for (int rr = 0; rr < 4; ++rr) {
        const float d = 1.0f + xs[mi][rr] + cs[ni] - 2.0f * acc[mi][ni][rr];
        const float q = __builtin_amdgcn_rcpf(d);  // d ~ 1000, 1 ulp is plenty
        acc[mi][ni][rr] = q;
        rp[mi][rr] += q;
      }

  #pragma unroll
  for (int mi = 0; mi < 4; ++mi)
    #pragma unroll
    for (int rr = 0; rr < 4; ++rr) {
      float v = rp[mi][rr];
      v += __shfl_xor(v, 1);
      v += __shfl_xor(v, 2);
      v += __shfl_xor(v, 4);
      v += __shfl_xor(v, 8);
      if (p == 0) atomicAdd(&lrow[mi * 16 + quad * 4 + rr], v);
    }
  __syncthreads();

  #pragma unroll
  for (int mi = 0; mi < 4; ++mi) {
    #pragma unroll
    for (int rr = 0; rr < 4; ++rr) {
      const int row = mi * 16 + quad * 4 + rr;
      const float inv = __builtin_amdgcn_rcpf(lrow[row]);
      float* orow = out + (size_t)(row0 + row) * K + wave * 64 + p;
      #pragma unroll
      for (int ni = 0; ni < 4; ++ni)
        orow[ni * 16] = acc[mi][ni][rr] * inv;
    }
  }
}

extern "C" void kernel_launch(void* const* d_in, const int* in_sizes, int n_in,
                              void* d_out, int out_size, void* d_ws, size_t ws_size,
                              hipStream_t stream) {
  const float* x    = (const float*)d_in[0];
  const float* cent = (const float*)d_in[1];
  float* out = (float*)d_out;

  // ws: csq[512] floats (2KB) | bbf bf16 image (512KB)
  float*    csq = (float*)d_ws;
  uint16_t* bbf = (uint16_t*)((char*)d_ws + 2048);

  const int N = in_sizes[0] / D;      // 65536
  prep_kernel<<<K, 64, 0, stream>>>(cent, csq, bbf);
  cluster_main<<<N / BM, THREADS, 0, stream>>>(x, bbf, csq, out);
}